// Round 10
// baseline (1940.159 us; speedup 1.0000x reference)
//
#include <hip/hip_runtime.h>

#define NB 4
#define NPT 16384
#define NPOINT 1024
#define NSAMPLE 32

#define FPS_T 512
#define FPS_PPT (NPT / FPS_T) /* 32 points per thread, idx = tid*32 + i */

#define BQ_WAVES 4
#define CAP 896

// ---------------------------------------------------------------------------
// Kernel 1: farthest point sampling. One block (512 thr / 8 waves) per batch.
// Bit-exact with the JAX reference: d = ((dx*dx+dy*dy)+dz*dz), contract off,
// argmax with first-index (lowest global idx) tie-break.
//
// Rounds 2/6/9 showed the 128-float private coordinate arrays are NEVER
// promoted to VGPRs (VGPR_Count=76 invariant; scratch/L2 re-read ~196KB/step
// = the 1.8ms). Fix: xy lives in LDS (128 KiB, i-major: sxy[i*512+t] ->
// byte addr t*8 + i*4096 -> conflict-free b64, immediate offsets), only
// z[32]+md[32] stay in registers (64 values -- the size class the allocator
// demonstrably promotes, cf. md at VGPR=76).
// ---------------------------------------------------------------------------
__global__ __launch_bounds__(FPS_T, 2) void fps_kernel(
    const float* __restrict__ pos, float* __restrict__ new_pos) {
#pragma clang fp contract(off)
  const int b = blockIdx.x;
  const int tid = threadIdx.x;
  const int wid = tid >> 6;
  const int lane = tid & 63;
  const float* __restrict__ p = pos + (size_t)b * NPT * 3;

  __shared__ float2 sxy[NPT]; // [i][t] i-major: sxy[i*512 + t], 128 KiB
  __shared__ unsigned long long red[3];

  float z[FPS_PPT], md[FPS_PPT];

  // load 32 consecutive points (384B) per thread via float4; xy -> LDS, z -> reg
  {
    const float4* pf4 = (const float4*)(p + (size_t)tid * (FPS_PPT * 3));
#pragma unroll
    for (int k = 0; k < FPS_PPT / 4; ++k) { // 8 groups of (3 float4 = 4 pts)
      const float4 a = pf4[3 * k + 0];
      const float4 bq = pf4[3 * k + 1];
      const float4 c = pf4[3 * k + 2];
      sxy[(4 * k + 0) * FPS_T + tid] = make_float2(a.x, a.y);
      z[4 * k + 0] = a.z;
      sxy[(4 * k + 1) * FPS_T + tid] = make_float2(a.w, bq.x);
      z[4 * k + 1] = bq.y;
      sxy[(4 * k + 2) * FPS_T + tid] = make_float2(bq.z, bq.w);
      z[4 * k + 2] = c.x;
      sxy[(4 * k + 3) * FPS_T + tid] = make_float2(c.y, c.z);
      z[4 * k + 3] = c.w;
    }
#pragma unroll
    for (int i = 0; i < FPS_PPT; ++i) md[i] = 1e10f;
  }

  if (tid < 3) red[tid] = 0ull;
  __syncthreads();

  float cx = p[0], cy = p[1], cz = p[2]; // far = 0 initially

  for (int j = 0; j < NPOINT; ++j) {
    if (tid == 0) {
      float* q = new_pos + ((size_t)b * NPOINT + j) * 3;
      q[0] = cx;
      q[1] = cy;
      q[2] = cz;
    }
    // ---- distance pass + per-thread argmax (first-i on ties) ---------------
    float bm = -1.0f;
    int bi = 0;
#pragma unroll
    for (int i = 0; i < FPS_PPT; ++i) {
      const float2 xy = sxy[i * FPS_T + tid];
      const float dx = xy.x - cx;
      const float dy = xy.y - cy;
      const float dz = z[i] - cz;
      const float d = (dx * dx + dy * dy) + dz * dz;
      const float m = fminf(md[i], d);
      md[i] = m;
      if (m > bm) { // strict: keeps lowest i on exact ties
        bm = m;
        bi = i;
      }
    }
    // ---- in-wave value max + lowest-lane resolve ---------------------------
    float wm = bm;
#pragma unroll
    for (int off = 1; off < 64; off <<= 1)
      wm = fmaxf(wm, __shfl_xor(wm, off, 64));
    const unsigned long long tied = __ballot(bm == wm);
    const int wl = __ffsll((long long)tied) - 1; // lowest tied lane = lowest idx
    const int wbi = __shfl(bi, wl, 64);
    const int widx = ((wid << 6) + wl) * FPS_PPT + wbi;
    // ---- cross-wave: one LDS u64 atomicMax ---------------------------------
    if (lane == 0) {
      const unsigned long long key =
          ((unsigned long long)__float_as_uint(wm) << 32) |
          (unsigned)(~widx);
      atomicMax(&red[j % 3], key);
    }
    __syncthreads();
    const unsigned long long w = red[j % 3];
    if (tid == 0) red[(j + 2) % 3] = 0ull; // 2 barriers from any prior use
    const int nf = (int)(~(unsigned)w);
    cx = p[nf * 3 + 0];
    cy = p[nf * 3 + 1];
    cz = p[nf * 3 + 2];
  }
}

// ---------------------------------------------------------------------------
// Kernel 2: fused ball query + grouping + shared MLP + max-pool.
// One wave per centroid, 4 waves per block. Selection = 32 smallest d2 within
// radius, ties by smaller index (== lax.top_k stable semantics).
// ---------------------------------------------------------------------------
__global__ __launch_bounds__(256) void bq_mlp_kernel(
    const float* __restrict__ pos, const float* __restrict__ x,
    const float* __restrict__ W1, const float* __restrict__ b1,
    const float* __restrict__ W2, const float* __restrict__ b2,
    const float* __restrict__ W3, const float* __restrict__ b3,
    const float* __restrict__ new_pos, float* __restrict__ out) {
#pragma clang fp contract(off)
  __shared__ __align__(16) float w1s[4 * 32];
  __shared__ __align__(16) float w2s[32 * 32];
  __shared__ __align__(16) float w3s[32 * 32];
  __shared__ float b1s[32], b2s[32], b3s[32];
  __shared__ unsigned long long list[BQ_WAVES][CAP];
  __shared__ int sel[BQ_WAVES][NSAMPLE];
  __shared__ unsigned cnt[BQ_WAVES];

  const int tid = threadIdx.x;
  const int wid = tid >> 6;
  const int lane = tid & 63;

  for (int i = tid; i < 128; i += 256) w1s[i] = W1[i];
  for (int i = tid; i < 1024; i += 256) {
    w2s[i] = W2[i];
    w3s[i] = W3[i];
  }
  if (tid < 32) {
    b1s[tid] = b1[tid];
    b2s[tid] = b2[tid];
    b3s[tid] = b3[tid];
  }
  if (lane == 0) cnt[wid] = 0u;
  __syncthreads();

  const int m_global = blockIdx.x * BQ_WAVES + wid; // 0..4095
  const int b = m_global >> 10;
  const float* __restrict__ p = pos + (size_t)b * NPT * 3;
  const float* __restrict__ xb = x + (size_t)b * NPT;

  const float cx = new_pos[(size_t)m_global * 3 + 0];
  const float cy = new_pos[(size_t)m_global * 3 + 1];
  const float cz = new_pos[(size_t)m_global * 3 + 2];
  const float snew = (cx * cx + cy * cy) + cz * cz;

  // ---- scan all points (4 per lane per iter, 48B/lane coalesced) -----------
  for (int it = 0; it < NPT / 256; ++it) {
    const int n0 = it * 256 + lane * 4;
    const float4* pf4 = (const float4*)(p + (size_t)n0 * 3);
    const float4 a = pf4[0];
    const float4 bq = pf4[1];
    const float4 c = pf4[2];
    float qx[4], qy[4], qz[4];
    qx[0] = a.x;  qy[0] = a.y;  qz[0] = a.z;
    qx[1] = a.w;  qy[1] = bq.x; qz[1] = bq.y;
    qx[2] = bq.z; qy[2] = bq.w; qz[2] = c.x;
    qx[3] = c.y;  qy[3] = c.z;  qz[3] = c.w;
#pragma unroll
    for (int t = 0; t < 4; ++t) {
      const float spos = (qx[t] * qx[t] + qy[t] * qy[t]) + qz[t] * qz[t];
      const float dot = (cx * qx[t] + cy * qy[t]) + cz * qz[t];
      const float d2 = (snew + spos) - 2.0f * dot; // reference op order
      if (d2 <= 0.01f) {
        const unsigned u = __float_as_uint(d2);
        const unsigned key = (u & 0x80000000u) ? ~u : (u | 0x80000000u);
        const unsigned li = atomicAdd(&cnt[wid], 1u);
        if (li < CAP)
          list[wid][li] = ((unsigned long long)key << 32) | (unsigned)(n0 + t);
      }
    }
  }
  __syncthreads();

  int c = (int)cnt[wid];
  if (c > CAP) c = CAP;
  const int nsel = c < NSAMPLE ? c : NSAMPLE;

  // ---- rank-select the 32 smallest (d2, idx) -------------------------------
  for (int i = lane; i < c; i += 64) {
    const unsigned long long ki = list[wid][i];
    int rank = 0;
    for (int jj = 0; jj < c; ++jj) rank += (list[wid][jj] < ki) ? 1 : 0;
    if (rank < NSAMPLE) sel[wid][rank] = (int)(unsigned)(ki & 0xFFFFFFFFull);
  }
  __syncthreads();

  // ---- MLP per selected sample (lanes 0..nsel-1), then max-pool ------------
  const bool active = (lane < nsel);
  const int n = sel[wid][active ? lane : 0];

  const float gpx = p[n * 3 + 0];
  const float gpy = p[n * 3 + 1];
  const float gpz = p[n * 3 + 2];
  const float gxv = xb[n];

  const float h0 = gpx - cx, h1i = gpy - cy, h2i = gpz - cz, h3i = gxv;

  float h1[32];
#pragma unroll
  for (int o = 0; o < 32; ++o) {
    float a = b1s[o];
    a += h0 * w1s[0 * 32 + o];
    a += h1i * w1s[1 * 32 + o];
    a += h2i * w1s[2 * 32 + o];
    a += h3i * w1s[3 * 32 + o];
    h1[o] = fmaxf(a, 0.0f);
  }

  float acc[32];
#pragma unroll
  for (int o = 0; o < 32; ++o) acc[o] = b2s[o];
  for (int k = 0; k < 32; ++k) {
    const float hk = h1[k];
    const float4* row = (const float4*)&w2s[k * 32];
#pragma unroll
    for (int q = 0; q < 8; ++q) {
      const float4 ww = row[q];
      acc[4 * q + 0] += hk * ww.x;
      acc[4 * q + 1] += hk * ww.y;
      acc[4 * q + 2] += hk * ww.z;
      acc[4 * q + 3] += hk * ww.w;
    }
  }
#pragma unroll
  for (int o = 0; o < 32; ++o) h1[o] = fmaxf(acc[o], 0.0f);

#pragma unroll
  for (int o = 0; o < 32; ++o) acc[o] = b3s[o];
  for (int k = 0; k < 32; ++k) {
    const float hk = h1[k];
    const float4* row = (const float4*)&w3s[k * 32];
#pragma unroll
    for (int q = 0; q < 8; ++q) {
      const float4 ww = row[q];
      acc[4 * q + 0] += hk * ww.x;
      acc[4 * q + 1] += hk * ww.y;
      acc[4 * q + 2] += hk * ww.z;
      acc[4 * q + 3] += hk * ww.w;
    }
  }
#pragma unroll
  for (int o = 0; o < 32; ++o)
    acc[o] = active ? fmaxf(acc[o], 0.0f) : -INFINITY;

#pragma unroll
  for (int mask = 1; mask <= 16; mask <<= 1) {
#pragma unroll
    for (int o = 0; o < 32; ++o)
      acc[o] = fmaxf(acc[o], __shfl_xor(acc[o], mask, 64));
  }

  if (lane == 0) {
    float4* o4 = (float4*)(out + (size_t)m_global * 32);
#pragma unroll
    for (int q = 0; q < 8; ++q)
      o4[q] = make_float4(acc[4 * q + 0], acc[4 * q + 1], acc[4 * q + 2],
                          acc[4 * q + 3]);
  }
}

// ---------------------------------------------------------------------------
extern "C" void kernel_launch(void* const* d_in, const int* in_sizes, int n_in,
                              void* d_out, int out_size, void* d_ws,
                              size_t ws_size, hipStream_t stream) {
  const float* pos = (const float*)d_in[0];
  const float* x = (const float*)d_in[1];
  const float* W1 = (const float*)d_in[2];
  const float* b1 = (const float*)d_in[3];
  const float* W2 = (const float*)d_in[4];
  const float* b2 = (const float*)d_in[5];
  const float* W3 = (const float*)d_in[6];
  const float* b3 = (const float*)d_in[7];
  float* out = (float*)d_out;
  float* new_pos = (float*)d_ws; // NB*NPOINT*3 floats = 48 KiB

  fps_kernel<<<NB, FPS_T, 0, stream>>>(pos, new_pos);
  bq_mlp_kernel<<<(NB * NPOINT) / BQ_WAVES, 256, 0, stream>>>(
      pos, x, W1, b1, W2, b2, W3, b3, new_pos, out);
}

// Round 12
// 1939.282 us; speedup vs baseline: 1.0005x; 1.0005x over previous
//
#include <hip/hip_runtime.h>

#define NB 4
#define NPT 16384
#define NPOINT 1024
#define NSAMPLE 32

#define FPS_T 512
#define FPS_PPT (NPT / FPS_T) /* 32 points per thread, idx = tid*32 + i */

#define BQ_WAVES 4
#define CAP 896

// ---------------------------------------------------------------------------
// DPP-based wave max step: v = max(v, dpp_shift(v)). bound_ctrl=true fills
// invalid source lanes with 0 -- harmless here because all reduced values
// are >= 0 (m = fmin(md>=0, d>=0)). CTRL must be a constant expression ->
// template parameter (r11 compile fix).
// ---------------------------------------------------------------------------
template <int CTRL>
__device__ __forceinline__ float dpp_max_step(float v) {
  const int s =
      __builtin_amdgcn_update_dpp(0, __float_as_int(v), CTRL, 0xf, 0xf, true);
  return fmaxf(v, __int_as_float(s));
}

// ---------------------------------------------------------------------------
// Kernel 1: farthest point sampling. One block (512 thr / 8 waves) per batch.
// Bit-exact with the JAX reference: d = ((dx*dx+dy*dy)+dz*dz), contract off,
// argmax with first-index (lowest global idx) tie-break.
//
// r10 falsified the "bulk traffic" theory (LDS move changed nothing). The
// invariant ~4300 cyc/step is the per-step SERIAL chain through the DS pipe:
// 6x ds_swizzle shfl (~700) + ds_bpermute (~120) + barrier w/ store drain
// (~250) + red read (~120) + dependent GLOBAL centroid fetch (~250). This
// version: DPP max reduce (VALU, ~80cyc), winner z tracked in-loop + tiny
// wzs[] LDS broadcast (no global fetch), rotating new_pos writer (drain paid
// 1/8 of steps per wave), paired float4 LDS reads (b128: DS pipe 2048->1536).
// ---------------------------------------------------------------------------
__global__ __launch_bounds__(FPS_T, 2) void fps_kernel(
    const float* __restrict__ pos, float* __restrict__ new_pos) {
#pragma clang fp contract(off)
  const int b = blockIdx.x;
  const int tid = threadIdx.x;
  const int wid = tid >> 6;
  const int lane = tid & 63;
  const float* __restrict__ p = pos + (size_t)b * NPT * 3;

  // paired xy plane: sxy4[(i>>1)*FPS_T + tid] = (x_i, y_i, x_{i+1}, y_{i+1})
  // for this thread's points idx = tid*32 + i (i even). 128 KiB.
  __shared__ float4 sxy4[NPT / 2];
  __shared__ unsigned long long red[3]; // (bits(max)<<32)|~idx, triple-buffered
  __shared__ float wzs[3][8];           // per-wave winner z, triple-buffered

  float z[FPS_PPT], md[FPS_PPT];

  // load 32 consecutive points (384B) per thread via float4; xy->LDS, z->reg
  {
    const float4* pf4 = (const float4*)(p + (size_t)tid * (FPS_PPT * 3));
#pragma unroll
    for (int k = 0; k < FPS_PPT / 4; ++k) { // 4 pts = 3 float4 per group
      const float4 a = pf4[3 * k + 0];
      const float4 bq = pf4[3 * k + 1];
      const float4 c = pf4[3 * k + 2];
      sxy4[(2 * k + 0) * FPS_T + tid] = make_float4(a.x, a.y, a.w, bq.x);
      sxy4[(2 * k + 1) * FPS_T + tid] = make_float4(bq.z, bq.w, c.y, c.z);
      z[4 * k + 0] = a.z;
      z[4 * k + 1] = bq.y;
      z[4 * k + 2] = c.x;
      z[4 * k + 3] = c.w;
    }
#pragma unroll
    for (int i = 0; i < FPS_PPT; ++i) md[i] = 1e10f;
  }

  if (tid < 3) red[tid] = 0ull;
  __syncthreads();

  float cx = p[0], cy = p[1], cz = p[2]; // far = 0 initially

  for (int j = 0; j < NPOINT; ++j) {
    // rotating writer: every thread has (cx,cy,cz); each wave pays the
    // store->barrier vmcnt drain only 1/8 of the steps
    if (tid == (((j & 7) << 6) | ((j >> 3) & 63))) {
      float* q = new_pos + ((size_t)b * NPOINT + j) * 3;
      q[0] = cx;
      q[1] = cy;
      q[2] = cz;
    }
    // ---- distance pass + per-thread argmax (first-i on ties) ---------------
    float bm = -1.0f;
    int bi = 0;
    float bz = 0.0f;
#pragma unroll
    for (int i2 = 0; i2 < FPS_PPT / 2; ++i2) {
      const float4 q4 = sxy4[i2 * FPS_T + tid];
      {
        const int i = 2 * i2;
        const float dx = q4.x - cx;
        const float dy = q4.y - cy;
        const float dz = z[i] - cz;
        const float d = (dx * dx + dy * dy) + dz * dz;
        const float m = fminf(md[i], d);
        md[i] = m;
        if (m > bm) { // strict: keeps lowest i on exact ties
          bm = m;
          bi = i;
          bz = z[i];
        }
      }
      {
        const int i = 2 * i2 + 1;
        const float dx = q4.z - cx;
        const float dy = q4.w - cy;
        const float dz = z[i] - cz;
        const float d = (dx * dx + dy * dy) + dz * dz;
        const float m = fminf(md[i], d);
        md[i] = m;
        if (m > bm) {
          bm = m;
          bi = i;
          bz = z[i];
        }
      }
    }
    // ---- in-wave argmax: DPP max chain (VALU) + ballot + readlane ----------
    float v = bm;
    v = dpp_max_step<0x111>(v); // row_shr:1
    v = dpp_max_step<0x112>(v); // row_shr:2
    v = dpp_max_step<0x114>(v); // row_shr:4
    v = dpp_max_step<0x118>(v); // row_shr:8
    v = dpp_max_step<0x142>(v); // row_bcast:15
    v = dpp_max_step<0x143>(v); // row_bcast:31 -> lane 63 has wave max
    const float wm =
        __int_as_float(__builtin_amdgcn_readlane(__float_as_int(v), 63));
    const unsigned long long tied = __ballot(bm == wm);
    const int wl = __ffsll((long long)tied) - 1; // lowest tied lane = lowest idx
    const int wbi = __builtin_amdgcn_readlane(bi, wl);
    const float wbz =
        __int_as_float(__builtin_amdgcn_readlane(__float_as_int(bz), wl));
    const int widx = ((wid << 6) + wl) * FPS_PPT + wbi;
    // ---- cross-wave: one LDS u64 atomicMax + winner-z stash ----------------
    if (lane == 0) {
      const unsigned long long key =
          ((unsigned long long)__float_as_uint(wm) << 32) |
          (unsigned)(~widx);
      atomicMax(&red[j % 3], key);
      wzs[j % 3][wid] = wbz;
    }
    __syncthreads();
    const unsigned long long w = red[j % 3];
    if (tid == 0) red[(j + 2) % 3] = 0ull; // 2 barriers from any prior use
    const int nf = (int)(~(unsigned)w);
    // next centroid entirely from LDS: z from winning wave's stash (wave =
    // nf>>11 since each wave owns 2048 consecutive idx), xy from sxy4
    cz = wzs[j % 3][nf >> 11];
    const int ot = nf >> 5; // owner tid
    const int oi = nf & 31; // owner slot
    const float4 q4 = sxy4[(oi >> 1) * FPS_T + ot];
    cx = (oi & 1) ? q4.z : q4.x;
    cy = (oi & 1) ? q4.w : q4.y;
  }
}

// ---------------------------------------------------------------------------
// Kernel 2: fused ball query + grouping + shared MLP + max-pool.
// One wave per centroid, 4 waves per block. Selection = 32 smallest d2 within
// radius, ties by smaller index (== lax.top_k stable semantics).
// ---------------------------------------------------------------------------
__global__ __launch_bounds__(256) void bq_mlp_kernel(
    const float* __restrict__ pos, const float* __restrict__ x,
    const float* __restrict__ W1, const float* __restrict__ b1,
    const float* __restrict__ W2, const float* __restrict__ b2,
    const float* __restrict__ W3, const float* __restrict__ b3,
    const float* __restrict__ new_pos, float* __restrict__ out) {
#pragma clang fp contract(off)
  __shared__ __align__(16) float w1s[4 * 32];
  __shared__ __align__(16) float w2s[32 * 32];
  __shared__ __align__(16) float w3s[32 * 32];
  __shared__ float b1s[32], b2s[32], b3s[32];
  __shared__ unsigned long long list[BQ_WAVES][CAP];
  __shared__ int sel[BQ_WAVES][NSAMPLE];
  __shared__ unsigned cnt[BQ_WAVES];

  const int tid = threadIdx.x;
  const int wid = tid >> 6;
  const int lane = tid & 63;

  for (int i = tid; i < 128; i += 256) w1s[i] = W1[i];
  for (int i = tid; i < 1024; i += 256) {
    w2s[i] = W2[i];
    w3s[i] = W3[i];
  }
  if (tid < 32) {
    b1s[tid] = b1[tid];
    b2s[tid] = b2[tid];
    b3s[tid] = b3[tid];
  }
  if (lane == 0) cnt[wid] = 0u;
  __syncthreads();

  const int m_global = blockIdx.x * BQ_WAVES + wid; // 0..4095
  const int b = m_global >> 10;
  const float* __restrict__ p = pos + (size_t)b * NPT * 3;
  const float* __restrict__ xb = x + (size_t)b * NPT;

  const float cx = new_pos[(size_t)m_global * 3 + 0];
  const float cy = new_pos[(size_t)m_global * 3 + 1];
  const float cz = new_pos[(size_t)m_global * 3 + 2];
  const float snew = (cx * cx + cy * cy) + cz * cz;

  // ---- scan all points (4 per lane per iter, 48B/lane coalesced) -----------
  for (int it = 0; it < NPT / 256; ++it) {
    const int n0 = it * 256 + lane * 4;
    const float4* pf4 = (const float4*)(p + (size_t)n0 * 3);
    const float4 a = pf4[0];
    const float4 bq = pf4[1];
    const float4 c = pf4[2];
    float qx[4], qy[4], qz[4];
    qx[0] = a.x;  qy[0] = a.y;  qz[0] = a.z;
    qx[1] = a.w;  qy[1] = bq.x; qz[1] = bq.y;
    qx[2] = bq.z; qy[2] = bq.w; qz[2] = c.x;
    qx[3] = c.y;  qy[3] = c.z;  qz[3] = c.w;
#pragma unroll
    for (int t = 0; t < 4; ++t) {
      const float spos = (qx[t] * qx[t] + qy[t] * qy[t]) + qz[t] * qz[t];
      const float dot = (cx * qx[t] + cy * qy[t]) + cz * qz[t];
      const float d2 = (snew + spos) - 2.0f * dot; // reference op order
      if (d2 <= 0.01f) {
        const unsigned u = __float_as_uint(d2);
        const unsigned key = (u & 0x80000000u) ? ~u : (u | 0x80000000u);
        const unsigned li = atomicAdd(&cnt[wid], 1u);
        if (li < CAP)
          list[wid][li] = ((unsigned long long)key << 32) | (unsigned)(n0 + t);
      }
    }
  }
  __syncthreads();

  int c = (int)cnt[wid];
  if (c > CAP) c = CAP;
  const int nsel = c < NSAMPLE ? c : NSAMPLE;

  // ---- rank-select the 32 smallest (d2, idx) -------------------------------
  for (int i = lane; i < c; i += 64) {
    const unsigned long long ki = list[wid][i];
    int rank = 0;
    for (int jj = 0; jj < c; ++jj) rank += (list[wid][jj] < ki) ? 1 : 0;
    if (rank < NSAMPLE) sel[wid][rank] = (int)(unsigned)(ki & 0xFFFFFFFFull);
  }
  __syncthreads();

  // ---- MLP per selected sample (lanes 0..nsel-1), then max-pool ------------
  const bool active = (lane < nsel);
  const int n = sel[wid][active ? lane : 0];

  const float gpx = p[n * 3 + 0];
  const float gpy = p[n * 3 + 1];
  const float gpz = p[n * 3 + 2];
  const float gxv = xb[n];

  const float h0 = gpx - cx, h1i = gpy - cy, h2i = gpz - cz, h3i = gxv;

  float h1[32];
#pragma unroll
  for (int o = 0; o < 32; ++o) {
    float a = b1s[o];
    a += h0 * w1s[0 * 32 + o];
    a += h1i * w1s[1 * 32 + o];
    a += h2i * w1s[2 * 32 + o];
    a += h3i * w1s[3 * 32 + o];
    h1[o] = fmaxf(a, 0.0f);
  }

  float acc[32];
#pragma unroll
  for (int o = 0; o < 32; ++o) acc[o] = b2s[o];
  for (int k = 0; k < 32; ++k) {
    const float hk = h1[k];
    const float4* row = (const float4*)&w2s[k * 32];
#pragma unroll
    for (int q = 0; q < 8; ++q) {
      const float4 ww = row[q];
      acc[4 * q + 0] += hk * ww.x;
      acc[4 * q + 1] += hk * ww.y;
      acc[4 * q + 2] += hk * ww.z;
      acc[4 * q + 3] += hk * ww.w;
    }
  }
#pragma unroll
  for (int o = 0; o < 32; ++o) h1[o] = fmaxf(acc[o], 0.0f);

#pragma unroll
  for (int o = 0; o < 32; ++o) acc[o] = b3s[o];
  for (int k = 0; k < 32; ++k) {
    const float hk = h1[k];
    const float4* row = (const float4*)&w3s[k * 32];
#pragma unroll
    for (int q = 0; q < 8; ++q) {
      const float4 ww = row[q];
      acc[4 * q + 0] += hk * ww.x;
      acc[4 * q + 1] += hk * ww.y;
      acc[4 * q + 2] += hk * ww.z;
      acc[4 * q + 3] += hk * ww.w;
    }
  }
#pragma unroll
  for (int o = 0; o < 32; ++o)
    acc[o] = active ? fmaxf(acc[o], 0.0f) : -INFINITY;

#pragma unroll
  for (int mask = 1; mask <= 16; mask <<= 1) {
#pragma unroll
    for (int o = 0; o < 32; ++o)
      acc[o] = fmaxf(acc[o], __shfl_xor(acc[o], mask, 64));
  }

  if (lane == 0) {
    float4* o4 = (float4*)(out + (size_t)m_global * 32);
#pragma unroll
    for (int q = 0; q < 8; ++q)
      o4[q] = make_float4(acc[4 * q + 0], acc[4 * q + 1], acc[4 * q + 2],
                          acc[4 * q + 3]);
  }
}

// ---------------------------------------------------------------------------
extern "C" void kernel_launch(void* const* d_in, const int* in_sizes, int n_in,
                              void* d_out, int out_size, void* d_ws,
                              size_t ws_size, hipStream_t stream) {
  const float* pos = (const float*)d_in[0];
  const float* x = (const float*)d_in[1];
  const float* W1 = (const float*)d_in[2];
  const float* b1 = (const float*)d_in[3];
  const float* W2 = (const float*)d_in[4];
  const float* b2 = (const float*)d_in[5];
  const float* W3 = (const float*)d_in[6];
  const float* b3 = (const float*)d_in[7];
  float* out = (float*)d_out;
  float* new_pos = (float*)d_ws; // NB*NPOINT*3 floats = 48 KiB

  fps_kernel<<<NB, FPS_T, 0, stream>>>(pos, new_pos);
  bq_mlp_kernel<<<(NB * NPOINT) / BQ_WAVES, 256, 0, stream>>>(
      pos, x, W1, b1, W2, b2, W3, b3, new_pos, out);
}

// Round 14
// 1914.031 us; speedup vs baseline: 1.0137x; 1.0132x over previous
//
#include <hip/hip_runtime.h>

#define NB 4
#define NPT 16384
#define NPOINT 1024
#define NSAMPLE 32

#define FPS_T 512
#define FPS_PPT (NPT / FPS_T) /* 32 points per thread, idx = tid*32 + i */

#define BQ_WAVES 4
#define CAP 896

template <int CTRL>
__device__ __forceinline__ float dpp_max_step(float v) {
  const int s =
      __builtin_amdgcn_update_dpp(0, __float_as_int(v), CTRL, 0xf, 0xf, true);
  return fmaxf(v, __int_as_float(s));
}

#define REP32(M)                                                              \
  M(0) M(1) M(2) M(3) M(4) M(5) M(6) M(7) M(8) M(9) M(10) M(11) M(12) M(13)  \
  M(14) M(15) M(16) M(17) M(18) M(19) M(20) M(21) M(22) M(23) M(24) M(25)    \
  M(26) M(27) M(28) M(29) M(30) M(31)

// ---------------------------------------------------------------------------
// Kernel 1: farthest point sampling. One block (512 thr / 8 waves) per batch.
// Bit-exact with the JAX reference: d = ((dx*dx+dy*dy)+dz*dz), contract off,
// argmax with first-index (lowest global idx) tie-break.
//
// r6/r9/r10/r12 invariance: the scan's DS/VMEM insts + the per-step global
// store's vmcnt drain at __syncthreads are the cost. This version:
// (1) coordinates + md live as 128 NAMED scalar floats (no arrays -> normal
//     register allocation, ~150 VGPR; scan is pure VALU, zero DS insts),
// (2) centroids logged to LDS, flushed once at the end (no global store,
//     hence no vmcnt(0) drain, inside the loop),
// (3) LDS keeps an i-major float2 (x,y) plane only for the single broadcast
//     winner-xy read per step; winner z comes from the per-wave stash.
// ---------------------------------------------------------------------------
__global__ __launch_bounds__(FPS_T, 2) void fps_kernel(
    const float* __restrict__ pos, float* __restrict__ new_pos) {
#pragma clang fp contract(off)
  const int b = blockIdx.x;
  const int tid = threadIdx.x;
  const int wid = tid >> 6;
  const int lane = tid & 63;
  const float* __restrict__ p = pos + (size_t)b * NPT * 3;

  __shared__ float2 sxy[NPT];           // i-major: sxy[i*FPS_T + tid], 128 KiB
  __shared__ float clog[NPOINT * 3];    // centroid log, 12 KiB
  __shared__ unsigned long long red[3]; // (bits(max)<<32)|~idx
  __shared__ float wzs[3][8];           // per-wave winner z

#define DECLPT(i) float X##i, Y##i, Z##i, MD##i;
  REP32(DECLPT)

  // load 32 consecutive points (384B) per thread via float4 -> named scalars
  {
    const float4* pf4 = (const float4*)(p + (size_t)tid * (FPS_PPT * 3));
#define LODQ(p0, p1, p2, p3, A, B, C)                                         \
  X##p0 = A.x; Y##p0 = A.y; Z##p0 = A.z;                                      \
  X##p1 = A.w; Y##p1 = B.x; Z##p1 = B.y;                                      \
  X##p2 = B.z; Y##p2 = B.w; Z##p2 = C.x;                                      \
  X##p3 = C.y; Y##p3 = C.z; Z##p3 = C.w;
    {
      const float4 A = pf4[0], B = pf4[1], C = pf4[2];
      LODQ(0, 1, 2, 3, A, B, C)
    }
    {
      const float4 A = pf4[3], B = pf4[4], C = pf4[5];
      LODQ(4, 5, 6, 7, A, B, C)
    }
    {
      const float4 A = pf4[6], B = pf4[7], C = pf4[8];
      LODQ(8, 9, 10, 11, A, B, C)
    }
    {
      const float4 A = pf4[9], B = pf4[10], C = pf4[11];
      LODQ(12, 13, 14, 15, A, B, C)
    }
    {
      const float4 A = pf4[12], B = pf4[13], C = pf4[14];
      LODQ(16, 17, 18, 19, A, B, C)
    }
    {
      const float4 A = pf4[15], B = pf4[16], C = pf4[17];
      LODQ(20, 21, 22, 23, A, B, C)
    }
    {
      const float4 A = pf4[18], B = pf4[19], C = pf4[20];
      LODQ(24, 25, 26, 27, A, B, C)
    }
    {
      const float4 A = pf4[21], B = pf4[22], C = pf4[23];
      LODQ(28, 29, 30, 31, A, B, C)
    }
  }
#define INITMD(i) MD##i = 1e10f;
  REP32(INITMD)
#define STASHXY(i) sxy[(i)*FPS_T + tid] = make_float2(X##i, Y##i);
  REP32(STASHXY)

  if (tid < 3) red[tid] = 0ull;
  __syncthreads();

  float cx = p[0], cy = p[1], cz = p[2]; // far = 0 initially

  for (int j = 0; j < NPOINT; ++j) {
    if (tid == 0) { // LDS log only -- no global store, no vmcnt drain
      clog[3 * j + 0] = cx;
      clog[3 * j + 1] = cy;
      clog[3 * j + 2] = cz;
    }
    // ---- distance pass (pure VALU) + per-thread argmax (first-i on ties) ---
    float bm = -1.0f;
    int bi = 0;
    float bz = 0.0f;
#define SCAN(i)                                                               \
  {                                                                           \
    const float dx = X##i - cx;                                               \
    const float dy = Y##i - cy;                                               \
    const float dz = Z##i - cz;                                               \
    const float d = (dx * dx + dy * dy) + dz * dz;                            \
    const float m = fminf(MD##i, d);                                          \
    MD##i = m;                                                                \
    if (m > bm) {                                                             \
      bm = m;                                                                 \
      bi = i;                                                                 \
      bz = Z##i;                                                              \
    }                                                                         \
  }
    REP32(SCAN)
    // ---- in-wave argmax: DPP max chain + ballot + readlane -----------------
    float v = bm;
    v = dpp_max_step<0x111>(v); // row_shr:1
    v = dpp_max_step<0x112>(v); // row_shr:2
    v = dpp_max_step<0x114>(v); // row_shr:4
    v = dpp_max_step<0x118>(v); // row_shr:8
    v = dpp_max_step<0x142>(v); // row_bcast:15
    v = dpp_max_step<0x143>(v); // row_bcast:31 -> lane 63 has wave max
    const float wm =
        __int_as_float(__builtin_amdgcn_readlane(__float_as_int(v), 63));
    const unsigned long long tied = __ballot(bm == wm);
    const int wl = __ffsll((long long)tied) - 1; // lowest tied lane
    const int wbi = __builtin_amdgcn_readlane(bi, wl);
    const float wbz =
        __int_as_float(__builtin_amdgcn_readlane(__float_as_int(bz), wl));
    const int widx = ((wid << 6) + wl) * FPS_PPT + wbi;
    // ---- cross-wave: one LDS u64 atomicMax + winner-z stash ----------------
    if (lane == 0) {
      const unsigned long long key =
          ((unsigned long long)__float_as_uint(wm) << 32) |
          (unsigned)(~widx);
      atomicMax(&red[j % 3], key);
      wzs[j % 3][wid] = wbz;
    }
    __syncthreads();
    const unsigned long long w = red[j % 3];
    if (tid == 0) red[(j + 2) % 3] = 0ull; // 2 barriers from any prior use
    const int nf = (int)(~(unsigned)w);
    cz = wzs[j % 3][nf >> 11]; // winning wave's z (2048 idx per wave)
    const int ot = nf >> 5;    // owner tid
    const int oi = nf & 31;    // owner slot
    const float2 cxy = sxy[oi * FPS_T + ot]; // broadcast read
    cx = cxy.x;
    cy = cxy.y;
  }

  __syncthreads();
  // flush centroid log to global, coalesced
  for (int k = tid; k < NPOINT * 3; k += FPS_T)
    new_pos[(size_t)b * NPOINT * 3 + k] = clog[k];
}

// ---------------------------------------------------------------------------
// Kernel 2: fused ball query + grouping + shared MLP + max-pool.
// One wave per centroid, 4 waves per block. Selection = 32 smallest d2 within
// radius, ties by smaller index (== lax.top_k stable semantics).
// ---------------------------------------------------------------------------
__global__ __launch_bounds__(256) void bq_mlp_kernel(
    const float* __restrict__ pos, const float* __restrict__ x,
    const float* __restrict__ W1, const float* __restrict__ b1,
    const float* __restrict__ W2, const float* __restrict__ b2,
    const float* __restrict__ W3, const float* __restrict__ b3,
    const float* __restrict__ new_pos, float* __restrict__ out) {
#pragma clang fp contract(off)
  __shared__ __align__(16) float w1s[4 * 32];
  __shared__ __align__(16) float w2s[32 * 32];
  __shared__ __align__(16) float w3s[32 * 32];
  __shared__ float b1s[32], b2s[32], b3s[32];
  __shared__ unsigned long long list[BQ_WAVES][CAP];
  __shared__ int sel[BQ_WAVES][NSAMPLE];
  __shared__ unsigned cnt[BQ_WAVES];

  const int tid = threadIdx.x;
  const int wid = tid >> 6;
  const int lane = tid & 63;

  for (int i = tid; i < 128; i += 256) w1s[i] = W1[i];
  for (int i = tid; i < 1024; i += 256) {
    w2s[i] = W2[i];
    w3s[i] = W3[i];
  }
  if (tid < 32) {
    b1s[tid] = b1[tid];
    b2s[tid] = b2[tid];
    b3s[tid] = b3[tid];
  }
  if (lane == 0) cnt[wid] = 0u;
  __syncthreads();

  const int m_global = blockIdx.x * BQ_WAVES + wid; // 0..4095
  const int b = m_global >> 10;
  const float* __restrict__ p = pos + (size_t)b * NPT * 3;
  const float* __restrict__ xb = x + (size_t)b * NPT;

  const float cx = new_pos[(size_t)m_global * 3 + 0];
  const float cy = new_pos[(size_t)m_global * 3 + 1];
  const float cz = new_pos[(size_t)m_global * 3 + 2];
  const float snew = (cx * cx + cy * cy) + cz * cz;

  // ---- scan all points (4 per lane per iter, 48B/lane coalesced) -----------
  for (int it = 0; it < NPT / 256; ++it) {
    const int n0 = it * 256 + lane * 4;
    const float4* pf4 = (const float4*)(p + (size_t)n0 * 3);
    const float4 a = pf4[0];
    const float4 bq = pf4[1];
    const float4 c = pf4[2];
    float qx[4], qy[4], qz[4];
    qx[0] = a.x;  qy[0] = a.y;  qz[0] = a.z;
    qx[1] = a.w;  qy[1] = bq.x; qz[1] = bq.y;
    qx[2] = bq.z; qy[2] = bq.w; qz[2] = c.x;
    qx[3] = c.y;  qy[3] = c.z;  qz[3] = c.w;
#pragma unroll
    for (int t = 0; t < 4; ++t) {
      const float spos = (qx[t] * qx[t] + qy[t] * qy[t]) + qz[t] * qz[t];
      const float dot = (cx * qx[t] + cy * qy[t]) + cz * qz[t];
      const float d2 = (snew + spos) - 2.0f * dot; // reference op order
      if (d2 <= 0.01f) {
        const unsigned u = __float_as_uint(d2);
        const unsigned key = (u & 0x80000000u) ? ~u : (u | 0x80000000u);
        const unsigned li = atomicAdd(&cnt[wid], 1u);
        if (li < CAP)
          list[wid][li] = ((unsigned long long)key << 32) | (unsigned)(n0 + t);
      }
    }
  }
  __syncthreads();

  int c = (int)cnt[wid];
  if (c > CAP) c = CAP;
  const int nsel = c < NSAMPLE ? c : NSAMPLE;

  // ---- rank-select the 32 smallest (d2, idx) -------------------------------
  for (int i = lane; i < c; i += 64) {
    const unsigned long long ki = list[wid][i];
    int rank = 0;
    for (int jj = 0; jj < c; ++jj) rank += (list[wid][jj] < ki) ? 1 : 0;
    if (rank < NSAMPLE) sel[wid][rank] = (int)(unsigned)(ki & 0xFFFFFFFFull);
  }
  __syncthreads();

  // ---- MLP per selected sample (lanes 0..nsel-1), then max-pool ------------
  const bool active = (lane < nsel);
  const int n = sel[wid][active ? lane : 0];

  const float gpx = p[n * 3 + 0];
  const float gpy = p[n * 3 + 1];
  const float gpz = p[n * 3 + 2];
  const float gxv = xb[n];

  const float h0 = gpx - cx, h1i = gpy - cy, h2i = gpz - cz, h3i = gxv;

  float h1[32];
#pragma unroll
  for (int o = 0; o < 32; ++o) {
    float a = b1s[o];
    a += h0 * w1s[0 * 32 + o];
    a += h1i * w1s[1 * 32 + o];
    a += h2i * w1s[2 * 32 + o];
    a += h3i * w1s[3 * 32 + o];
    h1[o] = fmaxf(a, 0.0f);
  }

  float acc[32];
#pragma unroll
  for (int o = 0; o < 32; ++o) acc[o] = b2s[o];
  for (int k = 0; k < 32; ++k) {
    const float hk = h1[k];
    const float4* row = (const float4*)&w2s[k * 32];
#pragma unroll
    for (int q = 0; q < 8; ++q) {
      const float4 ww = row[q];
      acc[4 * q + 0] += hk * ww.x;
      acc[4 * q + 1] += hk * ww.y;
      acc[4 * q + 2] += hk * ww.z;
      acc[4 * q + 3] += hk * ww.w;
    }
  }
#pragma unroll
  for (int o = 0; o < 32; ++o) h1[o] = fmaxf(acc[o], 0.0f);

#pragma unroll
  for (int o = 0; o < 32; ++o) acc[o] = b3s[o];
  for (int k = 0; k < 32; ++k) {
    const float hk = h1[k];
    const float4* row = (const float4*)&w3s[k * 32];
#pragma unroll
    for (int q = 0; q < 8; ++q) {
      const float4 ww = row[q];
      acc[4 * q + 0] += hk * ww.x;
      acc[4 * q + 1] += hk * ww.y;
      acc[4 * q + 2] += hk * ww.z;
      acc[4 * q + 3] += hk * ww.w;
    }
  }
#pragma unroll
  for (int o = 0; o < 32; ++o)
    acc[o] = active ? fmaxf(acc[o], 0.0f) : -INFINITY;

#pragma unroll
  for (int mask = 1; mask <= 16; mask <<= 1) {
#pragma unroll
    for (int o = 0; o < 32; ++o)
      acc[o] = fmaxf(acc[o], __shfl_xor(acc[o], mask, 64));
  }

  if (lane == 0) {
    float4* o4 = (float4*)(out + (size_t)m_global * 32);
#pragma unroll
    for (int q = 0; q < 8; ++q)
      o4[q] = make_float4(acc[4 * q + 0], acc[4 * q + 1], acc[4 * q + 2],
                          acc[4 * q + 3]);
  }
}

// ---------------------------------------------------------------------------
extern "C" void kernel_launch(void* const* d_in, const int* in_sizes, int n_in,
                              void* d_out, int out_size, void* d_ws,
                              size_t ws_size, hipStream_t stream) {
  const float* pos = (const float*)d_in[0];
  const float* x = (const float*)d_in[1];
  const float* W1 = (const float*)d_in[2];
  const float* b1 = (const float*)d_in[3];
  const float* W2 = (const float*)d_in[4];
  const float* b2 = (const float*)d_in[5];
  const float* W3 = (const float*)d_in[6];
  const float* b3 = (const float*)d_in[7];
  float* out = (float*)d_out;
  float* new_pos = (float*)d_ws; // NB*NPOINT*3 floats = 48 KiB

  fps_kernel<<<NB, FPS_T, 0, stream>>>(pos, new_pos);
  bq_mlp_kernel<<<(NB * NPOINT) / BQ_WAVES, 256, 0, stream>>>(
      pos, x, W1, b1, W2, b2, W3, b3, new_pos, out);
}